// Round 1
// baseline (869.718 us; speedup 1.0000x reference)
//
#include <hip/hip_runtime.h>

#define DEVINL __device__ __forceinline__

typedef unsigned short u16;
typedef __attribute__((ext_vector_type(8))) __bf16 bf16x8;
typedef __attribute__((ext_vector_type(4))) float f32x4;

struct alignas(8) u16x4 { u16 x, y, z, w; };

#define MFMA16(a, b, c) __builtin_amdgcn_mfma_f32_16x16x32_bf16(a, b, c, 0, 0, 0)

// fp32 -> bf16 round-to-nearest-even
DEVINL u16 f2bf(float f) {
  unsigned u = __builtin_bit_cast(unsigned, f);
  u += 0x7fffu + ((u >> 16) & 1u);
  return (u16)(u >> 16);
}

DEVINL void gload_lds16(const u16* g, u16* l) {
  __builtin_amdgcn_global_load_lds((const __attribute__((address_space(1))) void*)g,
                                   (__attribute__((address_space(3))) void*)l,
                                   16, 0, 0);
}

// Stage NR x 64-bf16 tile (128B rows, 8 x 16B chunks/row). 256 threads.
// Swizzled: LDS[r][c] <- G[r][c ^ (r&7)]  (LDS dest linear, source pre-swizzled)
template <int NR>
DEVINL void stage_n64(const u16* g, int ldg, u16* lds, int wave, int lane) {
#pragma unroll
  for (int t = 0; t < NR / 32; ++t) {
    int rb = (wave * (NR / 32) + t) * 8;
    int r = rb + (lane >> 3);
    int cg = (lane & 7) ^ (r & 7);
    gload_lds16(g + (size_t)r * ldg + cg * 8, lds + rb * 64);
  }
}

// Stage NR x 128-bf16 tile (256B rows, 16 x 16B chunks/row), XOR low 3 chunk bits.
template <int NR>
DEVINL void stage_n128(const u16* g, int ldg, u16* lds, int wave, int lane) {
#pragma unroll
  for (int t = 0; t < NR / 16; ++t) {
    int rb = (wave * (NR / 16) + t) * 4;
    int r = rb + (lane >> 4);
    int cg = (lane & 15) ^ (r & 7);
    gload_lds16(g + (size_t)r * ldg + cg * 8, lds + rb * 128);
  }
}

// Read a 16B MFMA fragment (8 contiguous bf16 along the fast dim) from swizzled tiles.
DEVINL bf16x8 frag64(const u16* lds, int row, int cg) {
  int c = cg ^ (row & 7);
  return *(const bf16x8*)(lds + row * 64 + c * 8);
}
DEVINL bf16x8 frag128(const u16* lds, int row, int cg) {
  int c = cg ^ (row & 7);
  return *(const bf16x8*)(lds + row * 128 + c * 8);
}

// ---------------- fp32 -> bf16 cast ----------------
__global__ void __launch_bounds__(256) k_cast(const float* __restrict__ src,
                                              u16* __restrict__ dst, int n4) {
  int i = blockIdx.x * blockDim.x + threadIdx.x;
  int stride = gridDim.x * blockDim.x;
  for (; i < n4; i += stride) {
    float4 f = ((const float4*)src)[i];
    u16x4 u;
    u.x = f2bf(f.x); u.y = f2bf(f.y); u.z = f2bf(f.z); u.w = f2bf(f.w);
    ((u16x4*)dst)[i] = u;
  }
}

// ---------------- shared GEMM mainloop ----------------
// C[128m x 128n] tile, A row-major (M,K), B row-major (N,K) (i.e. B^T input).
// 4 waves, wave w owns rows [w*32, w*32+32): acc[2 mf][8 nf] of 16x16 frags.
DEVINL void gemm_loop(const u16* Ag, const u16* Bg, int K, u16* As, u16* Bs,
                      f32x4 acc[2][8], int wave, int lane) {
  for (int kt = 0; kt < K; kt += 64) {
    __syncthreads();
    stage_n64<128>(Ag + kt, K, As, wave, lane);
    stage_n64<128>(Bg + kt, K, Bs, wave, lane);
    __syncthreads();
#pragma unroll
    for (int kk = 0; kk < 2; ++kk) {
      int cg = kk * 4 + (lane >> 4);
      bf16x8 a0 = frag64(As, wave * 32 + (lane & 15), cg);
      bf16x8 a1 = frag64(As, wave * 32 + 16 + (lane & 15), cg);
#pragma unroll
      for (int nf = 0; nf < 8; ++nf) {
        bf16x8 b = frag64(Bs, nf * 16 + (lane & 15), cg);
        acc[0][nf] = MFMA16(a0, b, acc[0][nf]);
        acc[1][nf] = MFMA16(a1, b, acc[1][nf]);
      }
    }
  }
}

// ---------------- GEMM1: qkv = x @ w_attn^T, fused RoPE + scatter ----------------
// grid (64 tm, 48 tn). tn: [0,16) q, [16,32) k, [32,48) v. Each n-tile == one head.
// q,k -> (B,H,T,D) with RoPE; v -> (B,H,D,T) transposed.
__global__ void __launch_bounds__(256) k_gemm_qkv(const u16* __restrict__ xb,
                                                  const u16* __restrict__ wab,
                                                  u16* __restrict__ qb,
                                                  u16* __restrict__ kb,
                                                  u16* __restrict__ vtb) {
  __shared__ u16 As[128 * 64];
  __shared__ u16 Bs[128 * 64];
  const int tm = blockIdx.x, tn = blockIdx.y;
  const int wave = threadIdx.x >> 6, lane = threadIdx.x & 63;

  f32x4 acc[2][8];
#pragma unroll
  for (int i = 0; i < 2; ++i)
#pragma unroll
    for (int n = 0; n < 8; ++n) acc[i][n] = f32x4{0.f, 0.f, 0.f, 0.f};

  gemm_loop(xb + (size_t)tm * 128 * 2048, wab + (size_t)tn * 128 * 2048, 2048,
            As, Bs, acc, wave, lane);

  const int sel = tn >> 4, h = tn & 15;
  const int m0 = tm * 128 + wave * 32;

  if (sel < 2) {
    u16* dst = sel ? kb : qb;
#pragma unroll
    for (int mf = 0; mf < 2; ++mf) {
#pragma unroll
      for (int j = 0; j < 4; ++j) {
        int gr = m0 + mf * 16 + (lane >> 4) * 4 + j;
        int b = gr >> 11, t = gr & 2047;
        size_t rowp = ((size_t)(b * 16 + h) * 2048 + t) * 128;
#pragma unroll
        for (int fn = 0; fn < 4; ++fn) {
          int d = fn * 16 + (lane & 15);  // d in [0,64)
          float lo = acc[mf][fn][j];
          float hi = acc[mf][fn + 4][j];
          // inv_freq = 10000^(-d/64) = exp(-d*ln(1e4)/64)
          float invf = __expf(-0.14391156631f * (float)d);
          float ang = (float)t * invf;
          float s, c;
          __sincosf(ang, &s, &c);
          dst[rowp + d] = f2bf(lo * c - hi * s);
          dst[rowp + d + 64] = f2bf(hi * c + lo * s);
        }
      }
    }
  } else {
    // v: transposed store (B,H,D,T); pack 4 consecutive t (the j dim) per store
#pragma unroll
    for (int mf = 0; mf < 2; ++mf) {
      int gr0 = m0 + mf * 16 + (lane >> 4) * 4;
      int b = gr0 >> 11, t0 = gr0 & 2047;
#pragma unroll
      for (int fn = 0; fn < 8; ++fn) {
        int d = fn * 16 + (lane & 15);
        u16x4 pk;
        pk.x = f2bf(acc[mf][fn][0]);
        pk.y = f2bf(acc[mf][fn][1]);
        pk.z = f2bf(acc[mf][fn][2]);
        pk.w = f2bf(acc[mf][fn][3]);
        *(u16x4*)(vtb + ((size_t)(b * 16 + h) * 128 + d) * 2048 + t0) = pk;
      }
    }
  }
}

// ---------------- flash attention (non-causal) ----------------
// grid (16 qt, 64 bh). 4 waves x 32 q-rows. KVBLK=64.
__global__ void __launch_bounds__(256) k_attn(const u16* __restrict__ qg,
                                              const u16* __restrict__ kg,
                                              const u16* __restrict__ vtg,
                                              u16* __restrict__ yg) {
  __shared__ u16 Ks[64 * 128];   // [kv][d]
  __shared__ u16 Vs[128 * 64];   // [d][kv] (global V already transposed)
  __shared__ u16 Ps[4 * 32 * 64];
  const int qt = blockIdx.x, bh = blockIdx.y;
  const int wave = threadIdx.x >> 6, lane = threadIdx.x & 63;
  const float SCALE = 0.08838834764831845f;  // 1/sqrt(128)

  const u16* qbh = qg + (size_t)bh * (2048 * 128);
  const u16* kbh = kg + (size_t)bh * (2048 * 128);
  const u16* vbh = vtg + (size_t)bh * (128 * 2048);
  u16* Pw = Ps + wave * (32 * 64);
  const int qrow0 = qt * 128 + wave * 32;

  // hoist Q fragments: A-operand, lane holds Q[q=l&15(+16mf)][d=kc*32+(l>>4)*8 ..+7]
  bf16x8 qf[2][4];
#pragma unroll
  for (int mf = 0; mf < 2; ++mf)
#pragma unroll
    for (int kc = 0; kc < 4; ++kc)
      qf[mf][kc] = *(const bf16x8*)(qbh +
          (size_t)(qrow0 + mf * 16 + (lane & 15)) * 128 + kc * 32 + (lane >> 4) * 8);

  f32x4 yacc[2][8];
#pragma unroll
  for (int i = 0; i < 2; ++i)
#pragma unroll
    for (int n = 0; n < 8; ++n) yacc[i][n] = f32x4{0.f, 0.f, 0.f, 0.f};
  float mI[2][4], lI[2][4];
#pragma unroll
  for (int i = 0; i < 2; ++i)
#pragma unroll
    for (int j = 0; j < 4; ++j) { mI[i][j] = -1e30f; lI[i][j] = 0.f; }

  for (int kv0 = 0; kv0 < 2048; kv0 += 64) {
    __syncthreads();
    stage_n128<64>(kbh + (size_t)kv0 * 128, 128, Ks, wave, lane);
    stage_n64<128>(vbh + kv0, 2048, Vs, wave, lane);
    __syncthreads();

    // S = Q K^T : D-layout row=q=(l>>4)*4+j (+16mf), col=kv=l&15 (+16nf)
    f32x4 sacc[2][4];
#pragma unroll
    for (int i = 0; i < 2; ++i)
#pragma unroll
      for (int n = 0; n < 4; ++n) sacc[i][n] = f32x4{0.f, 0.f, 0.f, 0.f};
#pragma unroll
    for (int kc = 0; kc < 4; ++kc) {
      int cg = kc * 4 + (lane >> 4);
#pragma unroll
      for (int nf = 0; nf < 4; ++nf) {
        bf16x8 bk = frag128(Ks, nf * 16 + (lane & 15), cg);
        sacc[0][nf] = MFMA16(qf[0][kc], bk, sacc[0][nf]);
        sacc[1][nf] = MFMA16(qf[1][kc], bk, sacc[1][nf]);
      }
    }

    // wave-parallel online softmax; rows are (l>>4)-group x reg j
#pragma unroll
    for (int mf = 0; mf < 2; ++mf) {
#pragma unroll
      for (int j = 0; j < 4; ++j) {
        float rmax = fmaxf(fmaxf(sacc[mf][0][j], sacc[mf][1][j]),
                           fmaxf(sacc[mf][2][j], sacc[mf][3][j])) * SCALE;
#pragma unroll
        for (int m = 1; m < 16; m <<= 1) rmax = fmaxf(rmax, __shfl_xor(rmax, m));
        float mold = mI[mf][j];
        float mnew = fmaxf(mold, rmax);
        float alpha = __expf(mold - mnew);
        float p[4];
        float rsum = 0.f;
#pragma unroll
        for (int nf = 0; nf < 4; ++nf) {
          p[nf] = __expf(sacc[mf][nf][j] * SCALE - mnew);
          rsum += p[nf];
        }
#pragma unroll
        for (int m = 1; m < 16; m <<= 1) rsum += __shfl_xor(rsum, m);
        lI[mf][j] = lI[mf][j] * alpha + rsum;
        mI[mf][j] = mnew;
#pragma unroll
        for (int nd = 0; nd < 8; ++nd) yacc[mf][nd][j] *= alpha;
        // write P (bf16) to per-wave LDS, swizzled (chunk ^= row&7)
        int qr = mf * 16 + (lane >> 4) * 4 + j;
        int swz = (qr & 7) << 3;
        u16* pw = Pw + qr * 64;
#pragma unroll
        for (int nf = 0; nf < 4; ++nf)
          pw[(nf * 16 + (lane & 15)) ^ swz] = f2bf(p[nf]);
      }
    }
    // forbid compiler reordering P reads before P writes (HW keeps same-wave DS in order)
    asm volatile("" ::: "memory");

    // PV: A = P [q][kv], B = V [kv][d] (from transposed Vs)
#pragma unroll
    for (int ks = 0; ks < 2; ++ks) {
      int cg = ks * 4 + (lane >> 4);
      bf16x8 pa0 = frag64(Pw, (lane & 15), cg);
      bf16x8 pa1 = frag64(Pw, 16 + (lane & 15), cg);
#pragma unroll
      for (int nd = 0; nd < 8; ++nd) {
        bf16x8 bv = frag64(Vs, nd * 16 + (lane & 15), cg);
        yacc[0][nd] = MFMA16(pa0, bv, yacc[0][nd]);
        yacc[1][nd] = MFMA16(pa1, bv, yacc[1][nd]);
      }
    }
  }

  // epilogue: y (B,T,H*D) bf16
  const int b = bh >> 4, h = bh & 15;
#pragma unroll
  for (int mf = 0; mf < 2; ++mf) {
#pragma unroll
    for (int j = 0; j < 4; ++j) {
      float inv = 1.f / lI[mf][j];
      int t = qrow0 + mf * 16 + (lane >> 4) * 4 + j;
      size_t rp = ((size_t)b * 2048 + t) * 2048 + h * 128;
#pragma unroll
      for (int nd = 0; nd < 8; ++nd)
        yg[rp + nd * 16 + (lane & 15)] = f2bf(yacc[mf][nd][j] * inv);
    }
  }
}

// ---------------- GEMM2: out = y @ w_proj^T (fp32 out) ----------------
__global__ void __launch_bounds__(256) k_gemm_proj(const u16* __restrict__ yb,
                                                   const u16* __restrict__ wpb,
                                                   float* __restrict__ out) {
  __shared__ u16 As[128 * 64];
  __shared__ u16 Bs[128 * 64];
  const int tm = blockIdx.x, tn = blockIdx.y;
  const int wave = threadIdx.x >> 6, lane = threadIdx.x & 63;

  f32x4 acc[2][8];
#pragma unroll
  for (int i = 0; i < 2; ++i)
#pragma unroll
    for (int n = 0; n < 8; ++n) acc[i][n] = f32x4{0.f, 0.f, 0.f, 0.f};

  gemm_loop(yb + (size_t)tm * 128 * 2048, wpb + (size_t)tn * 128 * 2048, 2048,
            As, Bs, acc, wave, lane);

  const int m0 = tm * 128 + wave * 32;
#pragma unroll
  for (int mf = 0; mf < 2; ++mf) {
#pragma unroll
    for (int j = 0; j < 4; ++j) {
      int gr = m0 + mf * 16 + (lane >> 4) * 4 + j;
      float* op = out + (size_t)gr * 2048 + tn * 128;
#pragma unroll
      for (int nf = 0; nf < 8; ++nf)
        op[nf * 16 + (lane & 15)] = acc[mf][nf][j];
    }
  }
}

// ---------------- launch ----------------
extern "C" void kernel_launch(void* const* d_in, const int* in_sizes, int n_in,
                              void* d_out, int out_size, void* d_ws, size_t ws_size,
                              hipStream_t stream) {
  const float* x = (const float*)d_in[0];
  const float* wa = (const float*)d_in[1];
  const float* wp = (const float*)d_in[2];
  float* out = (float*)d_out;

  // workspace layout (bf16 elems), total 192 MiB
  u16* xb = (u16*)d_ws;          // 8192x2048
  u16* wab = xb + 16777216;      // 6144x2048
  u16* wpb = wab + 12582912;     // 2048x2048
  u16* qb = wpb + 4194304;       // (B,H,T,D)
  u16* kb = qb + 16777216;       // (B,H,T,D)
  u16* vtb = kb + 16777216;      // (B,H,D,T)
  u16* yb = vtb + 16777216;      // (B,T,C)

  k_cast<<<dim3(2048), dim3(256), 0, stream>>>(x, xb, 4194304);
  k_cast<<<dim3(2048), dim3(256), 0, stream>>>(wa, wab, 3145728);
  k_cast<<<dim3(1024), dim3(256), 0, stream>>>(wp, wpb, 1048576);
  k_gemm_qkv<<<dim3(64, 48), dim3(256), 0, stream>>>(xb, wab, qb, kb, vtb);
  k_attn<<<dim3(16, 64), dim3(256), 0, stream>>>(qb, kb, vtb, yb);
  k_gemm_proj<<<dim3(64, 16), dim3(256), 0, stream>>>(yb, wpb, out);
}

// Round 2
// 635.655 us; speedup vs baseline: 1.3682x; 1.3682x over previous
//
#include <hip/hip_runtime.h>

#define DEVINL __device__ __forceinline__

typedef unsigned short u16;
typedef __attribute__((ext_vector_type(8))) __bf16 bf16x8;
typedef __attribute__((ext_vector_type(4))) float f32x4;
typedef __attribute__((ext_vector_type(16))) float f32x16;

struct alignas(8) u16x4 { u16 x, y, z, w; };

#define MFMA16(a, b, c) __builtin_amdgcn_mfma_f32_16x16x32_bf16(a, b, c, 0, 0, 0)
#define MFMA32(a, b, c) __builtin_amdgcn_mfma_f32_32x32x16_bf16(a, b, c, 0, 0, 0)

// fp32 -> bf16 round-to-nearest-even
DEVINL u16 f2bf(float f) {
  unsigned u = __builtin_bit_cast(unsigned, f);
  u += 0x7fffu + ((u >> 16) & 1u);
  return (u16)(u >> 16);
}

// packed f32x2 -> bf16x2 (RNE), lo = S0
DEVINL unsigned cvtpk_bf16(float lo, float hi) {
  unsigned r;
  asm("v_cvt_pk_bf16_f32 %0, %1, %2" : "=v"(r) : "v"(lo), "v"(hi));
  return r;
}

// swap: a' = {lo: own a, hi: partner's b}; b' = {lo: partner's a, hi: own b}
DEVINL void plane_swap(unsigned& a, unsigned& b) {
  asm("v_permlane32_swap_b32 %0, %1" : "+v"(a), "+v"(b));
}

DEVINL void gload_lds16(const u16* g, u16* l) {
  __builtin_amdgcn_global_load_lds((const __attribute__((address_space(1))) void*)g,
                                   (__attribute__((address_space(3))) void*)l,
                                   16, 0, 0);
}

// Stage NR x 64-bf16 tile (128B rows, 8 x 16B chunks/row). 256 threads.
// Swizzled: LDS[r][c] <- G[r][c ^ (r&7)]  (LDS dest linear, source pre-swizzled)
template <int NR>
DEVINL void stage_n64(const u16* g, int ldg, u16* lds, int wave, int lane) {
#pragma unroll
  for (int t = 0; t < NR / 32; ++t) {
    int rb = (wave * (NR / 32) + t) * 8;
    int r = rb + (lane >> 3);
    int cg = (lane & 7) ^ (r & 7);
    gload_lds16(g + (size_t)r * ldg + cg * 8, lds + rb * 64);
  }
}

// Stage NR x 128-bf16 tile (256B rows, 16 x 16B chunks/row), XOR low 3 chunk bits.
template <int NR>
DEVINL void stage_n128(const u16* g, int ldg, u16* lds, int wave, int lane) {
#pragma unroll
  for (int t = 0; t < NR / 16; ++t) {
    int rb = (wave * (NR / 16) + t) * 4;
    int r = rb + (lane >> 4);
    int cg = (lane & 15) ^ (r & 7);
    gload_lds16(g + (size_t)r * ldg + cg * 8, lds + rb * 128);
  }
}

// Read a 16B MFMA fragment (8 contiguous bf16 along the fast dim) from swizzled tiles.
DEVINL bf16x8 frag64(const u16* lds, int row, int cg) {
  int c = cg ^ (row & 7);
  return *(const bf16x8*)(lds + row * 64 + c * 8);
}
DEVINL bf16x8 frag128(const u16* lds, int row, int cg) {
  int c = cg ^ (row & 7);
  return *(const bf16x8*)(lds + row * 128 + c * 8);
}

// ---------------- fp32 -> bf16 cast ----------------
__global__ void __launch_bounds__(256) k_cast(const float* __restrict__ src,
                                              u16* __restrict__ dst, int n4) {
  int i = blockIdx.x * blockDim.x + threadIdx.x;
  int stride = gridDim.x * blockDim.x;
  for (; i < n4; i += stride) {
    float4 f = ((const float4*)src)[i];
    u16x4 u;
    u.x = f2bf(f.x); u.y = f2bf(f.y); u.z = f2bf(f.z); u.w = f2bf(f.w);
    ((u16x4*)dst)[i] = u;
  }
}

// ---------------- shared GEMM mainloop ----------------
// C[128m x 128n] tile, A row-major (M,K), B row-major (N,K) (i.e. B^T input).
// 4 waves, wave w owns rows [w*32, w*32+32): acc[2 mf][8 nf] of 16x16 frags.
DEVINL void gemm_loop(const u16* Ag, const u16* Bg, int K, u16* As, u16* Bs,
                      f32x4 acc[2][8], int wave, int lane) {
  for (int kt = 0; kt < K; kt += 64) {
    __syncthreads();
    stage_n64<128>(Ag + kt, K, As, wave, lane);
    stage_n64<128>(Bg + kt, K, Bs, wave, lane);
    __syncthreads();
#pragma unroll
    for (int kk = 0; kk < 2; ++kk) {
      int cg = kk * 4 + (lane >> 4);
      bf16x8 a0 = frag64(As, wave * 32 + (lane & 15), cg);
      bf16x8 a1 = frag64(As, wave * 32 + 16 + (lane & 15), cg);
#pragma unroll
      for (int nf = 0; nf < 8; ++nf) {
        bf16x8 b = frag64(Bs, nf * 16 + (lane & 15), cg);
        acc[0][nf] = MFMA16(a0, b, acc[0][nf]);
        acc[1][nf] = MFMA16(a1, b, acc[1][nf]);
      }
    }
  }
}

// ---------------- GEMM1: qkv = x @ w_attn^T, fused RoPE + scatter ----------------
// grid (64 tm, 48 tn). tn: [0,16) q, [16,32) k, [32,48) v. Each n-tile == one head.
// q (pre-scaled by 1/sqrt(D)), k -> (B,H,T,D) with RoPE; v -> (B,H,D,T) transposed.
__global__ void __launch_bounds__(256) k_gemm_qkv(const u16* __restrict__ xb,
                                                  const u16* __restrict__ wab,
                                                  u16* __restrict__ qb,
                                                  u16* __restrict__ kb,
                                                  u16* __restrict__ vtb) {
  __shared__ u16 As[128 * 64];
  __shared__ u16 Bs[128 * 64];
  const int tm = blockIdx.x, tn = blockIdx.y;
  const int wave = threadIdx.x >> 6, lane = threadIdx.x & 63;

  f32x4 acc[2][8];
#pragma unroll
  for (int i = 0; i < 2; ++i)
#pragma unroll
    for (int n = 0; n < 8; ++n) acc[i][n] = f32x4{0.f, 0.f, 0.f, 0.f};

  gemm_loop(xb + (size_t)tm * 128 * 2048, wab + (size_t)tn * 128 * 2048, 2048,
            As, Bs, acc, wave, lane);

  const int sel = tn >> 4, h = tn & 15;
  const int m0 = tm * 128 + wave * 32;

  if (sel < 2) {
    u16* dst = sel ? kb : qb;
    const float qs = sel ? 1.0f : 0.08838834764831845f;  // fold 1/sqrt(128) into q
#pragma unroll
    for (int mf = 0; mf < 2; ++mf) {
#pragma unroll
      for (int j = 0; j < 4; ++j) {
        int gr = m0 + mf * 16 + (lane >> 4) * 4 + j;
        int b = gr >> 11, t = gr & 2047;
        size_t rowp = ((size_t)(b * 16 + h) * 2048 + t) * 128;
#pragma unroll
        for (int fn = 0; fn < 4; ++fn) {
          int d = fn * 16 + (lane & 15);  // d in [0,64)
          float lo = acc[mf][fn][j];
          float hi = acc[mf][fn + 4][j];
          float invf = __expf(-0.14391156631f * (float)d);
          float ang = (float)t * invf;
          float s, c;
          __sincosf(ang, &s, &c);
          dst[rowp + d] = f2bf((lo * c - hi * s) * qs);
          dst[rowp + d + 64] = f2bf((hi * c + lo * s) * qs);
        }
      }
    }
  } else {
    // v: transposed store (B,H,D,T); pack 4 consecutive t (the j dim) per store
#pragma unroll
    for (int mf = 0; mf < 2; ++mf) {
      int gr0 = m0 + mf * 16 + (lane >> 4) * 4;
      int b = gr0 >> 11, t0 = gr0 & 2047;
#pragma unroll
      for (int fn = 0; fn < 8; ++fn) {
        int d = fn * 16 + (lane & 15);
        u16x4 pk;
        pk.x = f2bf(acc[mf][fn][0]);
        pk.y = f2bf(acc[mf][fn][1]);
        pk.z = f2bf(acc[mf][fn][2]);
        pk.w = f2bf(acc[mf][fn][3]);
        *(u16x4*)(vtb + ((size_t)(b * 16 + h) * 128 + d) * 2048 + t0) = pk;
      }
    }
  }
}

// ---------------- flash attention, swapped-QK^T 32x32 structure ----------------
// grid (16 qt, 64 bh), 4 waves x 32 q-rows, KVBLK=64, double-buffered K/V.
// S^T = mfma32(K, Q^T): lane holds S[q=lane&31][kv = h2*32 + (r&3)+8*(r>>2)+4*hi].
// Softmax fully in-register (31 ops + 1 shfl_xor(32)); P -> bf16 A-frags via
// cvt_pk + permlane32_swap (T12); defer-max rescale (T13, THR=8).
__global__ void __launch_bounds__(256) k_attn(const u16* __restrict__ qg,
                                              const u16* __restrict__ kg,
                                              const u16* __restrict__ vtg,
                                              u16* __restrict__ yg) {
  __shared__ u16 Ks[2][64 * 128];  // [buf][kv][d]
  __shared__ u16 Vs[2][128 * 64];  // [buf][d][kv]
  const int qt = blockIdx.x, bh = blockIdx.y;
  const int wave = threadIdx.x >> 6, lane = threadIdx.x & 63;
  const int hi = lane >> 5, ln = lane & 31;

  const u16* qbh = qg + (size_t)bh * (2048 * 128);
  const u16* kbh = kg + (size_t)bh * (2048 * 128);
  const u16* vbh = vtg + (size_t)bh * (128 * 2048);
  const int qrow0 = qt * 128 + wave * 32;

  // hoist Q (B-operand): lane holds Q[q=ln][d = kc*16 + hi*8 .. +7]
  bf16x8 qf[8];
#pragma unroll
  for (int kc = 0; kc < 8; ++kc)
    qf[kc] = *(const bf16x8*)(qbh + (size_t)(qrow0 + ln) * 128 + kc * 16 + hi * 8);

  f32x16 yacc[4];
#pragma unroll
  for (int nd = 0; nd < 4; ++nd)
#pragma unroll
    for (int r = 0; r < 16; ++r) yacc[nd][r] = 0.f;
  float m = -1e30f, l = 0.f;

  // prologue stage into buf 0
  stage_n128<64>(kbh, 128, Ks[0], wave, lane);
  stage_n64<128>(vbh, 2048, Vs[0], wave, lane);
  __syncthreads();

  int buf = 0;
  for (int kv0 = 0; kv0 < 2048; kv0 += 64) {
    // prefetch next tile into buf^1 (loads fly under this tile's compute)
    if (kv0 + 64 < 2048) {
      stage_n128<64>(kbh + (size_t)(kv0 + 64) * 128, 128, Ks[buf ^ 1], wave, lane);
      stage_n64<128>(vbh + kv0 + 64, 2048, Vs[buf ^ 1], wave, lane);
    }
    const u16* Kb = Ks[buf];
    const u16* Vb = Vs[buf];

    // QK^T: st[h2] = S^T[kv = h2*32 .. +32][q]
    f32x16 st[2];
#pragma unroll
    for (int h2 = 0; h2 < 2; ++h2)
#pragma unroll
      for (int r = 0; r < 16; ++r) st[h2][r] = 0.f;
#pragma unroll
    for (int kc = 0; kc < 8; ++kc) {
      bf16x8 a0 = frag128(Kb, ln, kc * 2 + hi);
      bf16x8 a1 = frag128(Kb, 32 + ln, kc * 2 + hi);
      st[0] = MFMA32(a0, qf[kc], st[0]);
      st[1] = MFMA32(a1, qf[kc], st[1]);
    }

    // tile max over this lane's 32 kv, then exchange with partner (lane^32)
    float t8[8];
#pragma unroll
    for (int i = 0; i < 8; ++i)
      t8[i] = fmaxf(fmaxf(st[0][i], st[0][i + 8]), fmaxf(st[1][i], st[1][i + 8]));
    float pmax = fmaxf(fmaxf(fmaxf(t8[0], t8[4]), fmaxf(t8[1], t8[5])),
                       fmaxf(fmaxf(t8[2], t8[6]), fmaxf(t8[3], t8[7])));
    pmax = fmaxf(pmax, __shfl_xor(pmax, 32));

    // defer-max (T13): only rescale when tile max grows past m + 8
    if (__any(pmax - m > 8.f)) {
      float mn = fmaxf(m, pmax);
      float al = __expf(m - mn);
      m = mn;
      l *= al;
#pragma unroll
      for (int nd = 0; nd < 4; ++nd)
#pragma unroll
        for (int r = 0; r < 16; ++r) yacc[nd][r] *= al;
    }

    // p = exp(s - m) in place + partial sums
    float sa0 = 0.f, sa1 = 0.f, sa2 = 0.f, sa3 = 0.f;
#pragma unroll
    for (int h2 = 0; h2 < 2; ++h2) {
#pragma unroll
      for (int r = 0; r < 16; ++r) {
        float e = __expf(st[h2][r] - m);
        st[h2][r] = e;
        if ((r & 3) == 0) sa0 += e;
        else if ((r & 3) == 1) sa1 += e;
        else if ((r & 3) == 2) sa2 += e;
        else sa3 += e;
      }
    }
    float ssum = (sa0 + sa1) + (sa2 + sa3);
    ssum += __shfl_xor(ssum, 32);
    l += ssum;

    // pack P to bf16 pairs: wa[h2][q8] = kv {h2*32+8*q8+4*hi +0,+1}, wb: +2,+3
    unsigned wa[2][4], wb[2][4];
#pragma unroll
    for (int h2 = 0; h2 < 2; ++h2)
#pragma unroll
      for (int q8 = 0; q8 < 4; ++q8) {
        wa[h2][q8] = cvtpk_bf16(st[h2][q8 * 4 + 0], st[h2][q8 * 4 + 1]);
        wb[h2][q8] = cvtpk_bf16(st[h2][q8 * 4 + 2], st[h2][q8 * 4 + 3]);
      }

    // PV: 4 kv16-blocks; pa[ks] assembled by permlane32_swap (both outputs used)
#pragma unroll
    for (int ks = 0; ks < 4; ++ks) {
      const int h2 = ks >> 1, k1 = ks & 1;
      unsigned w0 = wa[h2][2 * k1], w2 = wa[h2][2 * k1 + 1];
      plane_swap(w0, w2);
      unsigned w1 = wb[h2][2 * k1], w3 = wb[h2][2 * k1 + 1];
      plane_swap(w1, w3);
      union { unsigned u[4]; bf16x8 v; } pa;
      pa.u[0] = w0; pa.u[1] = w1; pa.u[2] = w2; pa.u[3] = w3;
#pragma unroll
      for (int nd = 0; nd < 4; ++nd) {
        bf16x8 bv = frag64(Vb, nd * 32 + ln, 2 * ks + hi);
        yacc[nd] = MFMA32(pa.v, bv, yacc[nd]);
      }
    }

    __syncthreads();  // drains prefetch vmcnt + protects buf swap
    buf ^= 1;
  }

  // epilogue: normalize rows by l[q] (held at lane q) and store y (B,T,H*D)
  const int b = bh >> 4, h = bh & 15;
  float inv = 1.f / l;
#pragma unroll
  for (int r = 0; r < 16; ++r) {
    int crow = (r & 3) + 8 * (r >> 2) + 4 * hi;
    float li = __shfl(inv, crow);
    int t = qrow0 + crow;
    size_t rp = ((size_t)b * 2048 + t) * 2048 + h * 128;
#pragma unroll
    for (int nd = 0; nd < 4; ++nd)
      yg[rp + nd * 32 + ln] = f2bf(yacc[nd][r] * li);
  }
}

// ---------------- GEMM2: out = y @ w_proj^T (fp32 out) ----------------
__global__ void __launch_bounds__(256) k_gemm_proj(const u16* __restrict__ yb,
                                                   const u16* __restrict__ wpb,
                                                   float* __restrict__ out) {
  __shared__ u16 As[128 * 64];
  __shared__ u16 Bs[128 * 64];
  const int tm = blockIdx.x, tn = blockIdx.y;
  const int wave = threadIdx.x >> 6, lane = threadIdx.x & 63;

  f32x4 acc[2][8];
#pragma unroll
  for (int i = 0; i < 2; ++i)
#pragma unroll
    for (int n = 0; n < 8; ++n) acc[i][n] = f32x4{0.f, 0.f, 0.f, 0.f};

  gemm_loop(yb + (size_t)tm * 128 * 2048, wpb + (size_t)tn * 128 * 2048, 2048,
            As, Bs, acc, wave, lane);

  const int m0 = tm * 128 + wave * 32;
#pragma unroll
  for (int mf = 0; mf < 2; ++mf) {
#pragma unroll
    for (int j = 0; j < 4; ++j) {
      int gr = m0 + mf * 16 + (lane >> 4) * 4 + j;
      float* op = out + (size_t)gr * 2048 + tn * 128;
#pragma unroll
      for (int nf = 0; nf < 8; ++nf)
        op[nf * 16 + (lane & 15)] = acc[mf][nf][j];
    }
  }
}

// ---------------- launch ----------------
extern "C" void kernel_launch(void* const* d_in, const int* in_sizes, int n_in,
                              void* d_out, int out_size, void* d_ws, size_t ws_size,
                              hipStream_t stream) {
  const float* x = (const float*)d_in[0];
  const float* wa = (const float*)d_in[1];
  const float* wp = (const float*)d_in[2];
  float* out = (float*)d_out;

  // workspace layout (bf16 elems), total 192 MiB
  u16* xb = (u16*)d_ws;          // 8192x2048
  u16* wab = xb + 16777216;      // 6144x2048
  u16* wpb = wab + 12582912;     // 2048x2048
  u16* qb = wpb + 4194304;       // (B,H,T,D), q pre-scaled by 1/sqrt(D)
  u16* kb = qb + 16777216;       // (B,H,T,D)
  u16* vtb = kb + 16777216;      // (B,H,D,T)
  u16* yb = vtb + 16777216;      // (B,T,C)

  k_cast<<<dim3(2048), dim3(256), 0, stream>>>(x, xb, 4194304);
  k_cast<<<dim3(2048), dim3(256), 0, stream>>>(wa, wab, 3145728);
  k_cast<<<dim3(1024), dim3(256), 0, stream>>>(wp, wpb, 1048576);
  k_gemm_qkv<<<dim3(64, 48), dim3(256), 0, stream>>>(xb, wab, qb, kb, vtb);
  k_attn<<<dim3(16, 64), dim3(256), 0, stream>>>(qb, kb, vtb, yb);
  k_gemm_proj<<<dim3(64, 16), dim3(256), 0, stream>>>(yb, wpb, out);
}